// Round 3
// baseline (345.517 us; speedup 1.0000x reference)
//
#include <hip/hip_runtime.h>

// ============================================================================
// ShiftedWindowAttention — bf16 MFMA pipeline, v3.
// B=16,H=W=64,C=256,NH=8,HD=32, win 8x8 (N=64), shift 4 -> 1024 windows.
//
// memset -> stats(q) -> finalize(q) -> rpbm -> gemm<0,1>(k)->klin+kstats ->
// finalize(k) -> gemm<1,0>(v_s)->vt0 -> gemm<1,0>(v_sh)->vt1 ->
// attn (QK+softmax once, PV both branches) -> proj(X_s) -> proj(X_sh).
//
// Round-3 changes: native __bf16 casts (v_cvt_pk_bf16_f32), BN=256 GEMMs
// (A fetched once), k-stats fused into gemm epilogue.
// ============================================================================

typedef unsigned short u16;
typedef unsigned int u32;
typedef __attribute__((ext_vector_type(8))) short bf16x8;   // 8 bf16 = 4 VGPR
typedef __attribute__((ext_vector_type(4))) float f32x4;

__device__ __forceinline__ float b2f(u16 u) {
  return __uint_as_float(((u32)u) << 16);
}
// native conversion -> compiler emits v_cvt_pk_bf16_f32 for pairs (RNE)
__device__ __forceinline__ u16 f2b(float f) {
  return __builtin_bit_cast(u16, (__bf16)f);
}
__device__ __forceinline__ u32 pk2(float a, float b) {
  return (u32)f2b(a) | ((u32)f2b(b) << 16);
}

// ---------------------------------------------------------------------------
// q stats: per (b,c) sum/sumsq over 4096 positions. 1024 blocks, float4 loads.
// ---------------------------------------------------------------------------
__global__ __launch_bounds__(256) void stats_f32(const float* __restrict__ src,
                                                 float* __restrict__ osum,
                                                 float* __restrict__ oss) {
  const int blk = blockIdx.x;      // 1024
  const int b = blk >> 6;
  const int p0 = (blk & 63) << 6;  // 64 positions per block
  const int t = threadIdx.x;
  const int c4 = (t & 63) << 2;
  const int pr = t >> 6;  // 0..3
  const float* p = src + ((((size_t)b << 12) + p0 + pr) << 8) + c4;
  float s[4] = {0.f, 0.f, 0.f, 0.f}, q[4] = {0.f, 0.f, 0.f, 0.f};
#pragma unroll
  for (int i = 0; i < 16; ++i) {
    float4 v = *(const float4*)(p + ((size_t)i << 10));
    s[0] += v.x; q[0] = fmaf(v.x, v.x, q[0]);
    s[1] += v.y; q[1] = fmaf(v.y, v.y, q[1]);
    s[2] += v.z; q[2] = fmaf(v.z, v.z, q[2]);
    s[3] += v.w; q[3] = fmaf(v.w, v.w, q[3]);
  }
#pragma unroll
  for (int j = 0; j < 4; ++j) {
    atomicAdd(&osum[(b << 8) + c4 + j], s[j]);
    atomicAdd(&oss[(b << 8) + c4 + j], q[j]);
  }
}

__global__ void finalize_stats(const float* __restrict__ sum,
                               const float* __restrict__ ss,
                               float* __restrict__ A, float* __restrict__ Bo,
                               float scale) {
  const int i = blockIdx.x * 256 + threadIdx.x;
  float m = sum[i] * (1.f / 4096.f);
  float v = ss[i] * (1.f / 4096.f) - m * m;
  float a = rsqrtf(v + 1e-5f) * scale;
  A[i] = a;
  Bo[i] = -m * a;
}

// ---------------------------------------------------------------------------
// rpb + mask fused, MFMA D-fragment order:
// rpbm[var][h][lane][cf*16 + rf*4 + r] ; n=16rf+4(lane>>4)+r, m=(lane&15)+16cf
// ---------------------------------------------------------------------------
__global__ __launch_bounds__(256) void rpbm_prep(const float* __restrict__ rpb,
                                                 float* __restrict__ rpbm) {
  const int idx = blockIdx.x * 256 + threadIdx.x;  // 131072
  const int t = idx & 63;
  const int lane = (idx >> 6) & 63;
  const int h = (idx >> 12) & 7;
  const int var = idx >> 15;
  const int cf = t >> 4, rf = (t >> 2) & 3, r = t & 3;
  const int n = ((lane >> 4) << 2) + r + (rf << 4);
  const int m = (lane & 15) + (cf << 4);
  const int vh = var >> 1, vw = var & 1;
  const int ln = (vh ? (1 + ((n >> 3) >= 4)) : 0) * 3 + (vw ? (1 + ((n & 7) >= 4)) : 0);
  const int lm = (vh ? (1 + ((m >> 3) >= 4)) : 0) * 3 + (vw ? (1 + ((m & 7) >= 4)) : 0);
  rpbm[idx] = rpb[(h << 12) + (n << 6) + m] + ((ln == lm) ? 0.f : -100.f);
}

// ---------------------------------------------------------------------------
// MFMA linear: dst = gather_window_shift(src) @ W^T + bias, stored bf16.
// BM=128, BN=256 (full), BK=64. 512 thr = 8 waves (2 row x 4 col of 64x64).
// MODE 0: row-major [row][256] (klin)  [+ STATS: fused per-(b,c) sum/ss]
// MODE 1: per-window transposed vt[(win*256+col)*64 + token], 8B stores.
// ---------------------------------------------------------------------------
template <int MODE, int STATS>
__global__ __launch_bounds__(512) void gemm_lin(const float* __restrict__ src,
                                                const float* __restrict__ W,
                                                const float* __restrict__ bias,
                                                u16* __restrict__ dst,
                                                float* __restrict__ osum,
                                                float* __restrict__ oss) {
  __shared__ u16 A_s[128][72];
  __shared__ u16 B_s[256][72];
  const int t = threadIdx.x;
  const int r0 = blockIdx.x << 7;

  // A staging: 4 thr/row, 16 f32 each
  const int srowA = t >> 2;
  const int kA0 = (t & 3) << 4;
  const int rg = r0 + srowA;
  const int bb = rg >> 12;
  const int rr = rg & 4095;
  const int wi = rr >> 6;
  const int nn = rr & 63;
  const int hs = ((wi >> 3) << 3) + (nn >> 3);
  const int wsq = ((wi & 7) << 3) + (nn & 7);
  const size_t abase =
      (((size_t)((bb << 6) | ((hs + 4) & 63)) << 6) | ((wsq + 4) & 63)) << 8;
  // B staging: 2 thr/row, 32 f32 each
  const int srowB = t >> 1;
  const int kB0 = (t & 1) << 5;
  const size_t wbase = (size_t)srowB << 8;

  const int wid = t >> 6, l = t & 63, u = l & 15, g = l >> 4;
  const int wr = wid >> 2, wc = wid & 3;

  f32x4 acc[4][4];
#pragma unroll
  for (int i = 0; i < 4; ++i)
#pragma unroll
    for (int j = 0; j < 4; ++j) acc[i][j] = {0.f, 0.f, 0.f, 0.f};

  for (int kk = 0; kk < 256; kk += 64) {
    __syncthreads();
    {
      const float* ap = src + abase + kk + kA0;
#pragma unroll
      for (int j = 0; j < 2; ++j) {
        float4 v0 = *(const float4*)(ap + (j << 3));
        float4 v1 = *(const float4*)(ap + (j << 3) + 4);
        uint4 w;
        w.x = pk2(v0.x, v0.y); w.y = pk2(v0.z, v0.w);
        w.z = pk2(v1.x, v1.y); w.w = pk2(v1.z, v1.w);
        *(uint4*)&A_s[srowA][kA0 + (j << 3)] = w;
      }
      const float* bp = W + wbase + kk + kB0;
#pragma unroll
      for (int j = 0; j < 4; ++j) {
        float4 v0 = *(const float4*)(bp + (j << 3));
        float4 v1 = *(const float4*)(bp + (j << 3) + 4);
        uint4 x;
        x.x = pk2(v0.x, v0.y); x.y = pk2(v0.z, v0.w);
        x.z = pk2(v1.x, v1.y); x.w = pk2(v1.z, v1.w);
        *(uint4*)&B_s[srowB][kB0 + (j << 3)] = x;
      }
    }
    __syncthreads();
#pragma unroll
    for (int ks = 0; ks < 2; ++ks) {
      bf16x8 a[4], bq[4];
#pragma unroll
      for (int rf = 0; rf < 4; ++rf)
        a[rf] = *(const bf16x8*)&A_s[(wr << 6) + (rf << 4) + u][(ks << 5) + (g << 3)];
#pragma unroll
      for (int cf = 0; cf < 4; ++cf)
        bq[cf] = *(const bf16x8*)&B_s[(wc << 6) + (cf << 4) + u][(ks << 5) + (g << 3)];
#pragma unroll
      for (int rf = 0; rf < 4; ++rf)
#pragma unroll
        for (int cf = 0; cf < 4; ++cf)
          acc[rf][cf] = __builtin_amdgcn_mfma_f32_16x16x32_bf16(a[rf], bq[cf],
                                                                acc[rf][cf], 0, 0, 0);
    }
  }

#pragma unroll
  for (int cf = 0; cf < 4; ++cf) {
    const int col = (wc << 6) + (cf << 4) + u;
    const float bv = bias[col];
    float s = 0.f, sq = 0.f;
#pragma unroll
    for (int rf = 0; rf < 4; ++rf) {
      const int row0 = r0 + (wr << 6) + (rf << 4) + (g << 2);
      if (MODE == 0) {
#pragma unroll
        for (int r = 0; r < 4; ++r) {
          u16 h = f2b(acc[rf][cf][r] + bv);
          dst[((size_t)(row0 + r) << 8) + col] = h;
          if (STATS) {
            float rv = b2f(h);
            s += rv;
            sq = fmaf(rv, rv, sq);
          }
        }
      } else {
        const int win = row0 >> 6;
        const int t0 = row0 & 63;
        u32 w0 = pk2(acc[rf][cf][0] + bv, acc[rf][cf][1] + bv);
        u32 w1 = pk2(acc[rf][cf][2] + bv, acc[rf][cf][3] + bv);
        *(uint2*)(dst + (((size_t)(win << 8) + col) << 6) + t0) = make_uint2(w0, w1);
      }
    }
    if (MODE == 0 && STATS) {
      s += __shfl_xor(s, 16);
      s += __shfl_xor(s, 32);
      sq += __shfl_xor(sq, 16);
      sq += __shfl_xor(sq, 32);
      if (g == 0) {
        const int b_ = r0 >> 12;
        atomicAdd(&osum[(b_ << 8) + col], s);
        atomicAdd(&oss[(b_ << 8) + col], sq);
      }
    }
  }
}

// ---------------------------------------------------------------------------
// Attention: one wave per (window, head). QK^T MFMA -> fragment softmax ->
// P bf16 LDS -> PV MFMA for both branches (V direct from global vt) ->
// X stored bf16 [row][256].
// ---------------------------------------------------------------------------
__global__ __launch_bounds__(256) void attn_mfma(
    const float* __restrict__ qsrc, const float* __restrict__ qA_,
    const float* __restrict__ qB_, const u16* __restrict__ klin,
    const float* __restrict__ kA_, const float* __restrict__ kB_,
    const u16* __restrict__ vt, const float* __restrict__ rpbm,
    u16* __restrict__ xs, u16* __restrict__ xsh) {
  __shared__ u16 P[4][64][72];
  const int tid = threadIdx.x;
  const int wid = tid >> 6;
  const int l = tid & 63;
  const int u = l & 15;
  const int g = l >> 4;
  const int task = blockIdx.x * 4 + wid;
  const int win = task >> 3;
  const int h = task & 7;
  const int b = win >> 6;
  const int wIdx = win & 63;
  const int wh = wIdx >> 3, ww = wIdx & 7;
  const int var = ((wh == 7) ? 2 : 0) | ((ww == 7) ? 1 : 0);
  const int coff = (h << 5) + (g << 3);

  float qav[8], qbv[8], kav[8], kbv[8];
  {
    const int o = (b << 8) + coff;
    float4 a0 = *(const float4*)(qA_ + o), a1 = *(const float4*)(qA_ + o + 4);
    float4 b0 = *(const float4*)(qB_ + o), b1 = *(const float4*)(qB_ + o + 4);
    float4 c0v = *(const float4*)(kA_ + o), c1 = *(const float4*)(kA_ + o + 4);
    float4 d0v = *(const float4*)(kB_ + o), d1 = *(const float4*)(kB_ + o + 4);
    qav[0]=a0.x;qav[1]=a0.y;qav[2]=a0.z;qav[3]=a0.w;qav[4]=a1.x;qav[5]=a1.y;qav[6]=a1.z;qav[7]=a1.w;
    qbv[0]=b0.x;qbv[1]=b0.y;qbv[2]=b0.z;qbv[3]=b0.w;qbv[4]=b1.x;qbv[5]=b1.y;qbv[6]=b1.z;qbv[7]=b1.w;
    kav[0]=c0v.x;kav[1]=c0v.y;kav[2]=c0v.z;kav[3]=c0v.w;kav[4]=c1.x;kav[5]=c1.y;kav[6]=c1.z;kav[7]=c1.w;
    kbv[0]=d0v.x;kbv[1]=d0v.y;kbv[2]=d0v.z;kbv[3]=d0v.w;kbv[4]=d1.x;kbv[5]=d1.y;kbv[6]=d1.z;kbv[7]=d1.w;
  }

  // q fragments (gathered + normalized + scaled)
  bf16x8 qf[4];
#pragma unroll
  for (int rf = 0; rf < 4; ++rf) {
    const int n = (rf << 4) + u;
    const int nhs = (wh << 3) + (n >> 3);
    const int nws = (ww << 3) + (n & 7);
    const float* qp = qsrc +
        ((((size_t)((b << 6) | ((nhs + 4) & 63)) << 6) | ((nws + 4) & 63)) << 8) + coff;
    float4 v0 = *(const float4*)qp;
    float4 v1 = *(const float4*)(qp + 4);
    float qv[8] = {v0.x, v0.y, v0.z, v0.w, v1.x, v1.y, v1.z, v1.w};
#pragma unroll
    for (int j = 0; j < 8; ++j) qf[rf][j] = (short)f2b(fmaf(qv[j], qav[j], qbv[j]));
  }

  // k fragments (bf16 + affine normalization)
  bf16x8 kf[4];
#pragma unroll
  for (int cf = 0; cf < 4; ++cf) {
    const int m = (cf << 4) + u;
    const u16* kp = klin + (((size_t)(win << 6) + m) << 8) + coff;
    union { uint4 v; u16 s[8]; } raw;
    raw.v = *(const uint4*)kp;
#pragma unroll
    for (int j = 0; j < 8; ++j)
      kf[cf][j] = (short)f2b(fmaf(b2f(raw.s[j]), kav[j], kbv[j]));
  }

  // S = q k^T
  f32x4 s[4][4];
  const f32x4 z4 = {0.f, 0.f, 0.f, 0.f};
#pragma unroll
  for (int rf = 0; rf < 4; ++rf)
#pragma unroll
    for (int cf = 0; cf < 4; ++cf)
      s[rf][cf] = __builtin_amdgcn_mfma_f32_16x16x32_bf16(qf[rf], kf[cf], z4, 0, 0, 0);

  // + rpb + mask (pre-fused, fragment order)
  const float* rb = rpbm + ((((var << 3) + h) << 6) + l) * 64;
#pragma unroll
  for (int cf = 0; cf < 4; ++cf)
#pragma unroll
    for (int rf = 0; rf < 4; ++rf) {
      float4 bv = *(const float4*)(rb + (cf << 4) + (rf << 2));
      s[rf][cf][0] += bv.x; s[rf][cf][1] += bv.y;
      s[rf][cf][2] += bv.z; s[rf][cf][3] += bv.w;
    }

  // softmax over m (4 col-frags x 16 lanes)
  f32x4 inv[4];
#pragma unroll
  for (int rf = 0; rf < 4; ++rf) {
#pragma unroll
    for (int r = 0; r < 4; ++r) {
      float m0 = fmaxf(fmaxf(s[rf][0][r], s[rf][1][r]),
                       fmaxf(s[rf][2][r], s[rf][3][r]));
      m0 = fmaxf(m0, __shfl_xor(m0, 1));
      m0 = fmaxf(m0, __shfl_xor(m0, 2));
      m0 = fmaxf(m0, __shfl_xor(m0, 4));
      m0 = fmaxf(m0, __shfl_xor(m0, 8));
      float t0 = 0.f;
#pragma unroll
      for (int cf = 0; cf < 4; ++cf) {
        s[rf][cf][r] = __expf(s[rf][cf][r] - m0);
        t0 += s[rf][cf][r];
      }
      t0 += __shfl_xor(t0, 1);
      t0 += __shfl_xor(t0, 2);
      t0 += __shfl_xor(t0, 4);
      t0 += __shfl_xor(t0, 8);
      inv[rf][r] = 1.f / t0;
    }
  }

  // P -> LDS (row-major [n][m], bf16)
#pragma unroll
  for (int rf = 0; rf < 4; ++rf)
#pragma unroll
    for (int r = 0; r < 4; ++r) {
      const int n = (rf << 4) + (g << 2) + r;
#pragma unroll
      for (int cf = 0; cf < 4; ++cf)
        P[wid][n][(cf << 4) + u] = f2b(s[rf][cf][r] * inv[rf][r]);
    }

  // PV both branches: Xt[d][n] = sum_m Vt[d][m] P[n][m]
#pragma unroll
  for (int br = 0; br < 2; ++br) {
    const u16* vb = vt + br * 16777216 + (((win << 8) + (h << 5) + u) << 6);
    bf16x8 vf[2][2];
#pragma unroll
    for (int df = 0; df < 2; ++df)
#pragma unroll
      for (int ks = 0; ks < 2; ++ks)
        vf[df][ks] = *(const bf16x8*)(vb + (df << 10) + (ks << 5) + (g << 3));
    f32x4 xt[2][4];
#pragma unroll
    for (int df = 0; df < 2; ++df)
#pragma unroll
      for (int cf = 0; cf < 4; ++cf) xt[df][cf] = z4;
#pragma unroll
    for (int cf = 0; cf < 4; ++cf)
#pragma unroll
      for (int ks = 0; ks < 2; ++ks) {
        bf16x8 pf = *(const bf16x8*)&P[wid][(cf << 4) + u][(ks << 5) + (g << 3)];
        xt[0][cf] = __builtin_amdgcn_mfma_f32_16x16x32_bf16(vf[0][ks], pf, xt[0][cf], 0, 0, 0);
        xt[1][cf] = __builtin_amdgcn_mfma_f32_16x16x32_bf16(vf[1][ks], pf, xt[1][cf], 0, 0, 0);
      }
    u16* xb = br ? xsh : xs;
#pragma unroll
    for (int df = 0; df < 2; ++df)
#pragma unroll
      for (int cf = 0; cf < 4; ++cf) {
        u32 w0 = pk2(xt[df][cf][0], xt[df][cf][1]);
        u32 w1 = pk2(xt[df][cf][2], xt[df][cf][3]);
        const size_t idx =
            (((size_t)(win << 6) + (cf << 4) + u) << 8) + (h << 5) + (df << 4) + (g << 2);
        *(uint2*)(xb + idx) = make_uint2(w0, w1);
      }
  }
}

// ---------------------------------------------------------------------------
// Proj GEMM: out = X @ pW^T + pb, fused reverse-shift scatter, f32 out.
// BM=128, BN=256, 512 thr.
// ---------------------------------------------------------------------------
__global__ __launch_bounds__(512) void proj_gemm(const u16* __restrict__ X,
                                                 const float* __restrict__ W,
                                                 const float* __restrict__ bias,
                                                 float* __restrict__ outp) {
  __shared__ u16 A_s[128][72];
  __shared__ u16 B_s[256][72];
  const int t = threadIdx.x;
  const int r0 = blockIdx.x << 7;
  const int srowA = t >> 2;
  const int kA0 = (t & 3) << 4;
  const int srowB = t >> 1;
  const int kB0 = (t & 1) << 5;
  const size_t abase = (size_t)(r0 + srowA) << 8;
  const size_t wbase = (size_t)srowB << 8;

  const int wid = t >> 6, l = t & 63, u = l & 15, g = l >> 4;
  const int wr = wid >> 2, wc = wid & 3;

  f32x4 acc[4][4];
#pragma unroll
  for (int i = 0; i < 4; ++i)
#pragma unroll
    for (int j = 0; j < 4; ++j) acc[i][j] = {0.f, 0.f, 0.f, 0.f};

  for (int kk = 0; kk < 256; kk += 64) {
    __syncthreads();
    {
      const u16* xp = X + abase + kk + kA0;
      *(uint4*)&A_s[srowA][kA0] = *(const uint4*)xp;
      *(uint4*)&A_s[srowA][kA0 + 8] = *(const uint4*)(xp + 8);
      const float* bp = W + wbase + kk + kB0;
#pragma unroll
      for (int j = 0; j < 4; ++j) {
        float4 v0 = *(const float4*)(bp + (j << 3));
        float4 v1 = *(const float4*)(bp + (j << 3) + 4);
        uint4 x;
        x.x = pk2(v0.x, v0.y); x.y = pk2(v0.z, v0.w);
        x.z = pk2(v1.x, v1.y); x.w = pk2(v1.z, v1.w);
        *(uint4*)&B_s[srowB][kB0 + (j << 3)] = x;
      }
    }
    __syncthreads();
#pragma unroll
    for (int ks = 0; ks < 2; ++ks) {
      bf16x8 a[4], bq[4];
#pragma unroll
      for (int rf = 0; rf < 4; ++rf)
        a[rf] = *(const bf16x8*)&A_s[(wr << 6) + (rf << 4) + u][(ks << 5) + (g << 3)];
#pragma unroll
      for (int cf = 0; cf < 4; ++cf)
        bq[cf] = *(const bf16x8*)&B_s[(wc << 6) + (cf << 4) + u][(ks << 5) + (g << 3)];
#pragma unroll
      for (int rf = 0; rf < 4; ++rf)
#pragma unroll
        for (int cf = 0; cf < 4; ++cf)
          acc[rf][cf] = __builtin_amdgcn_mfma_f32_16x16x32_bf16(a[rf], bq[cf],
                                                                acc[rf][cf], 0, 0, 0);
    }
  }

#pragma unroll
  for (int cf = 0; cf < 4; ++cf) {
    const int col = (wc << 6) + (cf << 4) + u;
    const float bv = bias[col];
#pragma unroll
    for (int rf = 0; rf < 4; ++rf) {
      const int row0 = r0 + (wr << 6) + (rf << 4) + (g << 2);
      const int win = row0 >> 6;
      const int n0 = row0 & 63;
      const int bb = win >> 6;
      const int wh = (win >> 3) & 7, ww = win & 7;
      const int nhs = (wh << 3) + (n0 >> 3);
      const int wsb = (ww << 3) + (n0 & 7);
#pragma unroll
      for (int r = 0; r < 4; ++r) {
        outp[((((size_t)((bb << 6) | ((nhs + 4) & 63)) << 6) | ((wsb + r + 4) & 63)) << 8) + col] =
            acc[rf][cf][r] + bv;
      }
    }
  }
}

// ---------------------------------------------------------------------------
extern "C" void kernel_launch(void* const* d_in, const int* in_sizes, int n_in,
                              void* d_out, int out_size, void* d_ws,
                              size_t ws_size, hipStream_t stream) {
  (void)in_sizes; (void)n_in; (void)out_size; (void)ws_size;
  const float* q   = (const float*)d_in[0];
  const float* k   = (const float*)d_in[1];
  const float* vs  = (const float*)d_in[2];
  const float* vsh = (const float*)d_in[3];
  const float* kW  = (const float*)d_in[4];
  const float* kb  = (const float*)d_in[5];
  const float* vWs = (const float*)d_in[6];
  const float* vbs = (const float*)d_in[7];
  const float* vWh = (const float*)d_in[8];
  const float* vbh = (const float*)d_in[9];
  const float* pW  = (const float*)d_in[10];
  const float* pb  = (const float*)d_in[11];
  const float* rpb = (const float*)d_in[12];
  float* out = (float*)d_out;

  float* f = (float*)d_ws;
  float* qsum = f;
  float* qss  = f + 4096;
  float* ksum = f + 8192;
  float* kss  = f + 12288;
  float* qA = f + 16384;
  float* qB = f + 20480;
  float* kA = f + 24576;
  float* kB = f + 28672;
  float* rpbm = f + 32768;                    // 131072 floats
  u16* klin = (u16*)(f + 163840);             // 16.7M u16
  u16* vt   = (u16*)(f + 8552448);            // 33.5M u16 (2 branches)
  u16* xsh  = (u16*)(f + 25329664);           // 16.7M u16
  u16* xs   = (u16*)(out + 16777216);         // parked in d_out hi half

  hipMemsetAsync(f, 0, 16384 * sizeof(float), stream);
  stats_f32<<<1024, 256, 0, stream>>>(q, qsum, qss);
  finalize_stats<<<16, 256, 0, stream>>>(qsum, qss, qA, qB,
                                         0.17677669529663687f);  // 1/sqrt(32)
  rpbm_prep<<<512, 256, 0, stream>>>(rpb, rpbm);

  gemm_lin<0, 1><<<512, 512, 0, stream>>>(k, kW, kb, klin, ksum, kss);
  finalize_stats<<<16, 256, 0, stream>>>(ksum, kss, kA, kB, 1.0f);

  gemm_lin<1, 0><<<512, 512, 0, stream>>>(vs, vWs, vbs, vt, nullptr, nullptr);
  gemm_lin<1, 0><<<512, 512, 0, stream>>>(vsh, vWh, vbh, vt + 16777216, nullptr, nullptr);

  attn_mfma<<<2048, 256, 0, stream>>>(q, qA, qB, klin, kA, kB, vt, rpbm, xs, xsh);

  proj_gemm<<<512, 512, 0, stream>>>(xs, pW, pb, out);
  proj_gemm<<<512, 512, 0, stream>>>(xsh, pW, pb, out + 16777216);
}

// Round 4
// 284.234 us; speedup vs baseline: 1.2156x; 1.2156x over previous
//
#include <hip/hip_runtime.h>

// ============================================================================
// ShiftedWindowAttention — bf16 MFMA pipeline, v4.
// B=16,H=W=64,C=256,NH=8,HD=32, win 8x8 (N=64), shift 4 -> 1024 windows.
//
// stats_f32(partials) -> finalize(q) -> rpbm -> gemm<0,1>(k)->klin+kpart ->
// finalize(k) -> gemm<1,0>(v_s) -> gemm<1,0>(v_sh) -> attn -> proj x2.
//
// Round-4 changes:
//  * all stats atomic-free (partial sums in ws + reduce kernel), no memset
//  * klin/vt stored in attention-fragment order: attn fragment loads are
//    64 lanes x 16B contiguous (were 16B per lane at 128-512B stride)
//  * xs moved to ws.
// ============================================================================

typedef unsigned short u16;
typedef unsigned int u32;
typedef __attribute__((ext_vector_type(8))) short bf16x8;   // 8 bf16 = 4 VGPR
typedef __attribute__((ext_vector_type(4))) float f32x4;

__device__ __forceinline__ float b2f(u16 u) {
  return __uint_as_float(((u32)u) << 16);
}
// native conversion -> v_cvt_pk_bf16_f32 (RNE)
__device__ __forceinline__ u16 f2b(float f) {
  return __builtin_bit_cast(u16, (__bf16)f);
}
__device__ __forceinline__ u32 pk2(float a, float b) {
  return (u32)f2b(a) | ((u32)f2b(b) << 16);
}

// ---------------------------------------------------------------------------
// q stats, atomic-free: block = (b, chunk of 64 positions), thread = channel.
// Writes per-block partial sum/sumsq to ps/pq[blk*256 + c].
// ---------------------------------------------------------------------------
__global__ __launch_bounds__(256) void stats_f32(const float* __restrict__ src,
                                                 float* __restrict__ ps,
                                                 float* __restrict__ pq) {
  const int blk = blockIdx.x;          // 1024 = b(16) * chunk(64)
  const int b = blk >> 6;
  const int p0 = (blk & 63) << 6;
  const int c = threadIdx.x;
  const float* p = src + (((size_t)(b << 12) + p0) << 8) + c;
  float s = 0.f, sq = 0.f;
#pragma unroll 8
  for (int i = 0; i < 64; ++i) {
    float v = p[(size_t)i << 8];
    s += v;
    sq = fmaf(v, v, sq);
  }
  ps[(blk << 8) + c] = s;
  pq[(blk << 8) + c] = sq;
}

// ---------------------------------------------------------------------------
// Reduce 64 partials per (b,c): A = rsqrt(var+eps)*scale ; B = -mean*A
// ---------------------------------------------------------------------------
__global__ void finalize_stats(const float* __restrict__ ps,
                               const float* __restrict__ pq,
                               float* __restrict__ A, float* __restrict__ Bo,
                               float scale) {
  const int i = blockIdx.x * 256 + threadIdx.x;  // 4096
  const int b = i >> 8, c = i & 255;
  const float* s0 = ps + ((size_t)(b << 6) << 8) + c;
  const float* q0 = pq + ((size_t)(b << 6) << 8) + c;
  float s = 0.f, sq = 0.f;
#pragma unroll 8
  for (int j = 0; j < 64; ++j) {
    s += s0[(size_t)j << 8];
    sq += q0[(size_t)j << 8];
  }
  float m = s * (1.f / 4096.f);
  float v = sq * (1.f / 4096.f) - m * m;
  float a = rsqrtf(v + 1e-5f) * scale;
  A[i] = a;
  Bo[i] = -m * a;
}

// ---------------------------------------------------------------------------
// rpb + mask fused, MFMA D-fragment order:
// rpbm[var][h][lane][cf*16 + rf*4 + r] ; n=16rf+4(lane>>4)+r, m=(lane&15)+16cf
// ---------------------------------------------------------------------------
__global__ __launch_bounds__(256) void rpbm_prep(const float* __restrict__ rpb,
                                                 float* __restrict__ rpbm) {
  const int idx = blockIdx.x * 256 + threadIdx.x;  // 131072
  const int t = idx & 63;
  const int lane = (idx >> 6) & 63;
  const int h = (idx >> 12) & 7;
  const int var = idx >> 15;
  const int cf = t >> 4, rf = (t >> 2) & 3, r = t & 3;
  const int n = ((lane >> 4) << 2) + r + (rf << 4);
  const int m = (lane & 15) + (cf << 4);
  const int vh = var >> 1, vw = var & 1;
  const int ln = (vh ? (1 + ((n >> 3) >= 4)) : 0) * 3 + (vw ? (1 + ((n & 7) >= 4)) : 0);
  const int lm = (vh ? (1 + ((m >> 3) >= 4)) : 0) * 3 + (vw ? (1 + ((m & 7) >= 4)) : 0);
  rpbm[idx] = rpb[(h << 12) + (n << 6) + m] + ((ln == lm) ? 0.f : -100.f);
}

// ---------------------------------------------------------------------------
// MFMA linear: dst = gather_window_shift(src) @ W^T + bias, stored bf16 in
// ATTENTION-FRAGMENT ORDER. BM=128, BN=256, BK=64; 512 thr = 8 waves (2x4).
// MODE 0 (klin):  [win][h][cf][g][u][8j]  (cf = token>>4, u = token&15,
//                  g = (ch>>3)&3, j = ch&7)          [+STATS partials]
// MODE 1 (vt):    [win][h][df][ks][g][u][8j] (df=(ch>>4)&1, u=ch&15,
//                  ks = tok>>5, g = (tok>>3)&3, j = tok&7)
// ---------------------------------------------------------------------------
template <int MODE, int STATS>
__global__ __launch_bounds__(512) void gemm_lin(const float* __restrict__ src,
                                                const float* __restrict__ W,
                                                const float* __restrict__ bias,
                                                u16* __restrict__ dst,
                                                float* __restrict__ kps,
                                                float* __restrict__ kpq) {
  __shared__ u16 A_s[128][72];
  __shared__ u16 B_s[256][72];
  const int t = threadIdx.x;
  const int r0 = blockIdx.x << 7;

  // A staging: 4 thr/row, 16 f32 each
  const int srowA = t >> 2;
  const int kA0 = (t & 3) << 4;
  const int rg = r0 + srowA;
  const int bb = rg >> 12;
  const int rr = rg & 4095;
  const int wi = rr >> 6;
  const int nn = rr & 63;
  const int hs = ((wi >> 3) << 3) + (nn >> 3);
  const int wsq = ((wi & 7) << 3) + (nn & 7);
  const size_t abase =
      (((size_t)((bb << 6) | ((hs + 4) & 63)) << 6) | ((wsq + 4) & 63)) << 8;
  // B staging: 2 thr/row, 32 f32 each
  const int srowB = t >> 1;
  const int kB0 = (t & 1) << 5;
  const size_t wbase = (size_t)srowB << 8;

  const int wid = t >> 6, l = t & 63, u = l & 15, g = l >> 4;
  const int wr = wid >> 2, wc = wid & 3;
  const int win = (blockIdx.x << 1) | wr;

  f32x4 acc[4][4];
#pragma unroll
  for (int i = 0; i < 4; ++i)
#pragma unroll
    for (int j = 0; j < 4; ++j) acc[i][j] = {0.f, 0.f, 0.f, 0.f};

  for (int kk = 0; kk < 256; kk += 64) {
    __syncthreads();
    {
      const float* ap = src + abase + kk + kA0;
#pragma unroll
      for (int j = 0; j < 2; ++j) {
        float4 v0 = *(const float4*)(ap + (j << 3));
        float4 v1 = *(const float4*)(ap + (j << 3) + 4);
        uint4 w;
        w.x = pk2(v0.x, v0.y); w.y = pk2(v0.z, v0.w);
        w.z = pk2(v1.x, v1.y); w.w = pk2(v1.z, v1.w);
        *(uint4*)&A_s[srowA][kA0 + (j << 3)] = w;
      }
      const float* bp = W + wbase + kk + kB0;
#pragma unroll
      for (int j = 0; j < 4; ++j) {
        float4 v0 = *(const float4*)(bp + (j << 3));
        float4 v1 = *(const float4*)(bp + (j << 3) + 4);
        uint4 x;
        x.x = pk2(v0.x, v0.y); x.y = pk2(v0.z, v0.w);
        x.z = pk2(v1.x, v1.y); x.w = pk2(v1.z, v1.w);
        *(uint4*)&B_s[srowB][kB0 + (j << 3)] = x;
      }
    }
    __syncthreads();
#pragma unroll
    for (int ks = 0; ks < 2; ++ks) {
      bf16x8 a[4], bq[4];
#pragma unroll
      for (int rf = 0; rf < 4; ++rf)
        a[rf] = *(const bf16x8*)&A_s[(wr << 6) + (rf << 4) + u][(ks << 5) + (g << 3)];
#pragma unroll
      for (int cf = 0; cf < 4; ++cf)
        bq[cf] = *(const bf16x8*)&B_s[(wc << 6) + (cf << 4) + u][(ks << 5) + (g << 3)];
#pragma unroll
      for (int rf = 0; rf < 4; ++rf)
#pragma unroll
        for (int cf = 0; cf < 4; ++cf)
          acc[rf][cf] = __builtin_amdgcn_mfma_f32_16x16x32_bf16(a[rf], bq[cf],
                                                                acc[rf][cf], 0, 0, 0);
    }
  }

#pragma unroll
  for (int cf = 0; cf < 4; ++cf) {
    const int col = (wc << 6) + (cf << 4) + u;
    const float bv = bias[col];
    float s = 0.f, sq = 0.f;
#pragma unroll
    for (int rf = 0; rf < 4; ++rf) {
      if (MODE == 0) {
        // klin: token t = (rf<<4) + (g<<2) + r ; channel = col
        const int hh = col >> 5;
        const int ga = (col >> 3) & 3;
        const int j = col & 7;
        const size_t base =
            ((size_t)((win << 3) | hh) << 11) + (rf << 9) + (ga << 7) + j;
#pragma unroll
        for (int r = 0; r < 4; ++r) {
          u16 hv = f2b(acc[rf][cf][r] + bv);
          dst[base + (((g << 2) + r) << 3)] = hv;
          if (STATS) {
            float rv = b2f(hv);
            s += rv;
            sq = fmaf(rv, rv, sq);
          }
        }
      } else {
        // vt: d-channel = col, token t = (rf<<4)+(g<<2)+r
        const int hh = (wc << 1) | (cf >> 1);
        const int df = cf & 1;
        const int ks = rf >> 1;
        const int ga = ((rf & 1) << 1) | (g >> 1);
        const size_t base = ((size_t)((win << 3) | hh) << 11) + (df << 10) +
                            (ks << 9) + (ga << 7) + (u << 3) + ((g & 1) << 2);
        u32 w0 = pk2(acc[rf][cf][0] + bv, acc[rf][cf][1] + bv);
        u32 w1 = pk2(acc[rf][cf][2] + bv, acc[rf][cf][3] + bv);
        *(uint2*)(dst + base) = make_uint2(w0, w1);
      }
    }
    if (MODE == 0 && STATS) {
      s += __shfl_xor(s, 16);
      s += __shfl_xor(s, 32);
      sq += __shfl_xor(sq, 16);
      sq += __shfl_xor(sq, 32);
      if (g == 0) {
        const int row = (blockIdx.x << 1) | wr;   // 0..1023, b = row>>6
        kps[(row << 8) + col] = s;
        kpq[(row << 8) + col] = sq;
      }
    }
  }
}

// ---------------------------------------------------------------------------
// Attention: one wave per (window, head). QK^T MFMA -> fragment softmax ->
// P bf16 LDS -> PV MFMA both branches (V/K fragment-ordered, coalesced) ->
// X stored bf16 [row][256].
// ---------------------------------------------------------------------------
__global__ __launch_bounds__(256) void attn_mfma(
    const float* __restrict__ qsrc, const float* __restrict__ qA_,
    const float* __restrict__ qB_, const u16* __restrict__ klin,
    const float* __restrict__ kA_, const float* __restrict__ kB_,
    const u16* __restrict__ vt, const float* __restrict__ rpbm,
    u16* __restrict__ xs, u16* __restrict__ xsh) {
  __shared__ u16 P[4][64][72];
  const int tid = threadIdx.x;
  const int wid = tid >> 6;
  const int l = tid & 63;
  const int u = l & 15;
  const int g = l >> 4;
  const int task = blockIdx.x * 4 + wid;
  const int win = task >> 3;
  const int h = task & 7;
  const int b = win >> 6;
  const int wIdx = win & 63;
  const int wh = wIdx >> 3, ww = wIdx & 7;
  const int var = ((wh == 7) ? 2 : 0) | ((ww == 7) ? 1 : 0);
  const int coff = (h << 5) + (g << 3);

  float qav[8], qbv[8], kav[8], kbv[8];
  {
    const int o = (b << 8) + coff;
    float4 a0 = *(const float4*)(qA_ + o), a1 = *(const float4*)(qA_ + o + 4);
    float4 b0 = *(const float4*)(qB_ + o), b1 = *(const float4*)(qB_ + o + 4);
    float4 c0v = *(const float4*)(kA_ + o), c1 = *(const float4*)(kA_ + o + 4);
    float4 d0v = *(const float4*)(kB_ + o), d1 = *(const float4*)(kB_ + o + 4);
    qav[0]=a0.x;qav[1]=a0.y;qav[2]=a0.z;qav[3]=a0.w;qav[4]=a1.x;qav[5]=a1.y;qav[6]=a1.z;qav[7]=a1.w;
    qbv[0]=b0.x;qbv[1]=b0.y;qbv[2]=b0.z;qbv[3]=b0.w;qbv[4]=b1.x;qbv[5]=b1.y;qbv[6]=b1.z;qbv[7]=b1.w;
    kav[0]=c0v.x;kav[1]=c0v.y;kav[2]=c0v.z;kav[3]=c0v.w;kav[4]=c1.x;kav[5]=c1.y;kav[6]=c1.z;kav[7]=c1.w;
    kbv[0]=d0v.x;kbv[1]=d0v.y;kbv[2]=d0v.z;kbv[3]=d0v.w;kbv[4]=d1.x;kbv[5]=d1.y;kbv[6]=d1.z;kbv[7]=d1.w;
  }

  // q fragments (gathered + normalized + scaled)
  bf16x8 qf[4];
#pragma unroll
  for (int rf = 0; rf < 4; ++rf) {
    const int n = (rf << 4) + u;
    const int nhs = (wh << 3) + (n >> 3);
    const int nws = (ww << 3) + (n & 7);
    const float* qp = qsrc +
        ((((size_t)((b << 6) | ((nhs + 4) & 63)) << 6) | ((nws + 4) & 63)) << 8) + coff;
    float4 v0 = *(const float4*)qp;
    float4 v1 = *(const float4*)(qp + 4);
    float qv[8] = {v0.x, v0.y, v0.z, v0.w, v1.x, v1.y, v1.z, v1.w};
#pragma unroll
    for (int j = 0; j < 8; ++j) qf[rf][j] = (short)f2b(fmaf(qv[j], qav[j], qbv[j]));
  }

  // k fragments — fragment-ordered klin: wave read = 64 lanes x 16B contiguous
  const u16* kp = klin + ((size_t)((win << 3) | h) << 11);
  bf16x8 kf[4];
#pragma unroll
  for (int cf = 0; cf < 4; ++cf) {
    union { uint4 v; u16 s[8]; } raw;
    raw.v = *(const uint4*)(kp + (cf << 9) + (g << 7) + (u << 3));
#pragma unroll
    for (int j = 0; j < 8; ++j)
      kf[cf][j] = (short)f2b(fmaf(b2f(raw.s[j]), kav[j], kbv[j]));
  }

  // S = q k^T
  f32x4 s[4][4];
  const f32x4 z4 = {0.f, 0.f, 0.f, 0.f};
#pragma unroll
  for (int rf = 0; rf < 4; ++rf)
#pragma unroll
    for (int cf = 0; cf < 4; ++cf)
      s[rf][cf] = __builtin_amdgcn_mfma_f32_16x16x32_bf16(qf[rf], kf[cf], z4, 0, 0, 0);

  // + rpb + mask (pre-fused, fragment order)
  const float* rb = rpbm + ((((var << 3) + h) << 6) + l) * 64;
#pragma unroll
  for (int cf = 0; cf < 4; ++cf)
#pragma unroll
    for (int rf = 0; rf < 4; ++rf) {
      float4 bv = *(const float4*)(rb + (cf << 4) + (rf << 2));
      s[rf][cf][0] += bv.x; s[rf][cf][1] += bv.y;
      s[rf][cf][2] += bv.z; s[rf][cf][3] += bv.w;
    }

  // softmax over m (4 col-frags x 16 lanes)
  f32x4 inv[4];
#pragma unroll
  for (int rf = 0; rf < 4; ++rf) {
#pragma unroll
    for (int r = 0; r < 4; ++r) {
      float m0 = fmaxf(fmaxf(s[rf][0][r], s[rf][1][r]),
                       fmaxf(s[rf][2][r], s[rf][3][r]));
      m0 = fmaxf(m0, __shfl_xor(m0, 1));
      m0 = fmaxf(m0, __shfl_xor(m0, 2));
      m0 = fmaxf(m0, __shfl_xor(m0, 4));
      m0 = fmaxf(m0, __shfl_xor(m0, 8));
      float t0 = 0.f;
#pragma unroll
      for (int cf = 0; cf < 4; ++cf) {
        s[rf][cf][r] = __expf(s[rf][cf][r] - m0);
        t0 += s[rf][cf][r];
      }
      t0 += __shfl_xor(t0, 1);
      t0 += __shfl_xor(t0, 2);
      t0 += __shfl_xor(t0, 4);
      t0 += __shfl_xor(t0, 8);
      inv[rf][r] = 1.f / t0;
    }
  }

  // P -> LDS (row-major [n][m], bf16)
#pragma unroll
  for (int rf = 0; rf < 4; ++rf)
#pragma unroll
    for (int r = 0; r < 4; ++r) {
      const int n = (rf << 4) + (g << 2) + r;
#pragma unroll
      for (int cf = 0; cf < 4; ++cf)
        P[wid][n][(cf << 4) + u] = f2b(s[rf][cf][r] * inv[rf][r]);
    }

  // PV both branches: Xt[d][n] = sum_m Vt[d][m] P[n][m]
#pragma unroll
  for (int br = 0; br < 2; ++br) {
    const u16* vb = vt + br * 16777216 + ((size_t)((win << 3) | h) << 11);
    bf16x8 vf[2][2];
#pragma unroll
    for (int df = 0; df < 2; ++df)
#pragma unroll
      for (int ks = 0; ks < 2; ++ks)
        vf[df][ks] = *(const bf16x8*)(vb + (df << 10) + (ks << 9) + (g << 7) + (u << 3));
    f32x4 xt[2][4];
#pragma unroll
    for (int df = 0; df < 2; ++df)
#pragma unroll
      for (int cf = 0; cf < 4; ++cf) xt[df][cf] = z4;
#pragma unroll
    for (int cf = 0; cf < 4; ++cf)
#pragma unroll
      for (int ks = 0; ks < 2; ++ks) {
        bf16x8 pf = *(const bf16x8*)&P[wid][(cf << 4) + u][(ks << 5) + (g << 3)];
        xt[0][cf] = __builtin_amdgcn_mfma_f32_16x16x32_bf16(vf[0][ks], pf, xt[0][cf], 0, 0, 0);
        xt[1][cf] = __builtin_amdgcn_mfma_f32_16x16x32_bf16(vf[1][ks], pf, xt[1][cf], 0, 0, 0);
      }
    u16* xb = br ? xsh : xs;
#pragma unroll
    for (int df = 0; df < 2; ++df)
#pragma unroll
      for (int cf = 0; cf < 4; ++cf) {
        u32 w0 = pk2(xt[df][cf][0], xt[df][cf][1]);
        u32 w1 = pk2(xt[df][cf][2], xt[df][cf][3]);
        const size_t idx =
            (((size_t)(win << 6) + (cf << 4) + u) << 8) + (h << 5) + (df << 4) + (g << 2);
        *(uint2*)(xb + idx) = make_uint2(w0, w1);
      }
  }
}

// ---------------------------------------------------------------------------
// Proj GEMM: out = X @ pW^T + pb, fused reverse-shift scatter, f32 out.
// BM=128, BN=256, 512 thr.
// ---------------------------------------------------------------------------
__global__ __launch_bounds__(512) void proj_gemm(const u16* __restrict__ X,
                                                 const float* __restrict__ W,
                                                 const float* __restrict__ bias,
                                                 float* __restrict__ outp) {
  __shared__ u16 A_s[128][72];
  __shared__ u16 B_s[256][72];
  const int t = threadIdx.x;
  const int r0 = blockIdx.x << 7;
  const int srowA = t >> 2;
  const int kA0 = (t & 3) << 4;
  const int srowB = t >> 1;
  const int kB0 = (t & 1) << 5;
  const size_t abase = (size_t)(r0 + srowA) << 8;
  const size_t wbase = (size_t)srowB << 8;

  const int wid = t >> 6, l = t & 63, u = l & 15, g = l >> 4;
  const int wr = wid >> 2, wc = wid & 3;

  f32x4 acc[4][4];
#pragma unroll
  for (int i = 0; i < 4; ++i)
#pragma unroll
    for (int j = 0; j < 4; ++j) acc[i][j] = {0.f, 0.f, 0.f, 0.f};

  for (int kk = 0; kk < 256; kk += 64) {
    __syncthreads();
    {
      const u16* xp = X + abase + kk + kA0;
      *(uint4*)&A_s[srowA][kA0] = *(const uint4*)xp;
      *(uint4*)&A_s[srowA][kA0 + 8] = *(const uint4*)(xp + 8);
      const float* bp = W + wbase + kk + kB0;
#pragma unroll
      for (int j = 0; j < 4; ++j) {
        float4 v0 = *(const float4*)(bp + (j << 3));
        float4 v1 = *(const float4*)(bp + (j << 3) + 4);
        uint4 x;
        x.x = pk2(v0.x, v0.y); x.y = pk2(v0.z, v0.w);
        x.z = pk2(v1.x, v1.y); x.w = pk2(v1.z, v1.w);
        *(uint4*)&B_s[srowB][kB0 + (j << 3)] = x;
      }
    }
    __syncthreads();
#pragma unroll
    for (int ks = 0; ks < 2; ++ks) {
      bf16x8 a[4], bq[4];
#pragma unroll
      for (int rf = 0; rf < 4; ++rf)
        a[rf] = *(const bf16x8*)&A_s[(wr << 6) + (rf << 4) + u][(ks << 5) + (g << 3)];
#pragma unroll
      for (int cf = 0; cf < 4; ++cf)
        bq[cf] = *(const bf16x8*)&B_s[(wc << 6) + (cf << 4) + u][(ks << 5) + (g << 3)];
#pragma unroll
      for (int rf = 0; rf < 4; ++rf)
#pragma unroll
        for (int cf = 0; cf < 4; ++cf)
          acc[rf][cf] = __builtin_amdgcn_mfma_f32_16x16x32_bf16(a[rf], bq[cf],
                                                                acc[rf][cf], 0, 0, 0);
    }
  }

#pragma unroll
  for (int cf = 0; cf < 4; ++cf) {
    const int col = (wc << 6) + (cf << 4) + u;
    const float bv = bias[col];
#pragma unroll
    for (int rf = 0; rf < 4; ++rf) {
      const int row0 = r0 + (wr << 6) + (rf << 4) + (g << 2);
      const int win = row0 >> 6;
      const int n0 = row0 & 63;
      const int bb = win >> 6;
      const int wh = (win >> 3) & 7, ww = win & 7;
      const int nhs = (wh << 3) + (n0 >> 3);
      const int wsb = (ww << 3) + (n0 & 7);
#pragma unroll
      for (int r = 0; r < 4; ++r) {
        outp[((((size_t)((bb << 6) | ((nhs + 4) & 63)) << 6) | ((wsb + r + 4) & 63)) << 8) + col] =
            acc[rf][cf][r] + bv;
      }
    }
  }
}

// ---------------------------------------------------------------------------
extern "C" void kernel_launch(void* const* d_in, const int* in_sizes, int n_in,
                              void* d_out, int out_size, void* d_ws,
                              size_t ws_size, hipStream_t stream) {
  (void)in_sizes; (void)n_in; (void)out_size; (void)ws_size;
  const float* q   = (const float*)d_in[0];
  const float* k   = (const float*)d_in[1];
  const float* vs  = (const float*)d_in[2];
  const float* vsh = (const float*)d_in[3];
  const float* kW  = (const float*)d_in[4];
  const float* kb  = (const float*)d_in[5];
  const float* vWs = (const float*)d_in[6];
  const float* vbs = (const float*)d_in[7];
  const float* vWh = (const float*)d_in[8];
  const float* vbh = (const float*)d_in[9];
  const float* pW  = (const float*)d_in[10];
  const float* pb  = (const float*)d_in[11];
  const float* rpb = (const float*)d_in[12];
  float* out = (float*)d_out;

  float* f = (float*)d_ws;
  float* qps = f;                       // 262144
  float* qpq = f + 262144;              // 262144
  float* kps = f + 524288;              // 262144
  float* kpq = f + 786432;              // 262144
  float* qA  = f + 1048576;
  float* qB  = f + 1052672;
  float* kA  = f + 1056768;
  float* kB  = f + 1060864;
  float* rpbm = f + 1064960;            // 131072
  u16* klin = (u16*)(f + 1196032);      // 16.77M u16 (8388608 f32)
  u16* vt   = (u16*)(f + 9584640);      // 33.55M u16 (2 branches)
  u16* xsh  = (u16*)(f + 26361856);     // 16.77M u16
  u16* xs   = (u16*)(f + 34750464);     // 16.77M u16

  stats_f32<<<1024, 256, 0, stream>>>(q, qps, qpq);
  finalize_stats<<<16, 256, 0, stream>>>(qps, qpq, qA, qB,
                                         0.17677669529663687f);  // 1/sqrt(32)
  rpbm_prep<<<512, 256, 0, stream>>>(rpb, rpbm);

  gemm_lin<0, 1><<<512, 512, 0, stream>>>(k, kW, kb, klin, kps, kpq);
  finalize_stats<<<16, 256, 0, stream>>>(kps, kpq, kA, kB, 1.0f);

  gemm_lin<1, 0><<<512, 512, 0, stream>>>(vs, vWs, vbs, vt, nullptr, nullptr);
  gemm_lin<1, 0><<<512, 512, 0, stream>>>(vsh, vWh, vbh, vt + 16777216, nullptr, nullptr);

  attn_mfma<<<2048, 256, 0, stream>>>(q, qA, qB, klin, kA, kB, vt, rpbm, xs, xsh);

  proj_gemm<<<512, 512, 0, stream>>>(xs, pW, pb, out);
  proj_gemm<<<512, 512, 0, stream>>>(xsh, pW, pb, out + 16777216);
}

// Round 5
// 224.721 us; speedup vs baseline: 1.5375x; 1.2648x over previous
//
#include <hip/hip_runtime.h>

// ============================================================================
// ShiftedWindowAttention — bf16 MFMA pipeline, v5 (fused attn+proj).
// B=16,H=W=64,C=256,NH=8,HD=32, win 8x8 (N=64), shift 4 -> 1024 windows.
//
// stats_f32 -> finalize(q) -> rpbm -> pwf_prep -> gemm<0,1>(k)->klin+kpart ->
// finalize(k) -> gemm<1,0>(v_s & v_sh, one launch) -> attn_mega (QK+softmax
// once, per branch: PV -> X in LDS -> cooperative proj -> shifted store).
//
// Round-5 changes:
//  * proj fused into attention (xs/xsh HBM round-trip eliminated, 2 launches
//    gone); X lives in 33.8KB LDS per window, proj weights pre-converted to
//    fragment-ordered bf16 (L2-resident).
//  * v_scale/v_shift GEMMs merged into one launch (grid.y = branch).
// ============================================================================

typedef unsigned short u16;
typedef unsigned int u32;
typedef __attribute__((ext_vector_type(8))) short bf16x8;   // 8 bf16 = 4 VGPR
typedef __attribute__((ext_vector_type(4))) float f32x4;

__device__ __forceinline__ float b2f(u16 u) {
  return __uint_as_float(((u32)u) << 16);
}
// native conversion -> v_cvt_pk_bf16_f32 (RNE)
__device__ __forceinline__ u16 f2b(float f) {
  return __builtin_bit_cast(u16, (__bf16)f);
}
__device__ __forceinline__ u32 pk2(float a, float b) {
  return (u32)f2b(a) | ((u32)f2b(b) << 16);
}

// ---------------------------------------------------------------------------
// q stats, atomic-free partials.
// ---------------------------------------------------------------------------
__global__ __launch_bounds__(256) void stats_f32(const float* __restrict__ src,
                                                 float* __restrict__ ps,
                                                 float* __restrict__ pq) {
  const int blk = blockIdx.x;          // 1024 = b(16) * chunk(64)
  const int b = blk >> 6;
  const int p0 = (blk & 63) << 6;
  const int c = threadIdx.x;
  const float* p = src + (((size_t)(b << 12) + p0) << 8) + c;
  float s = 0.f, sq = 0.f;
#pragma unroll 8
  for (int i = 0; i < 64; ++i) {
    float v = p[(size_t)i << 8];
    s += v;
    sq = fmaf(v, v, sq);
  }
  ps[(blk << 8) + c] = s;
  pq[(blk << 8) + c] = sq;
}

__global__ void finalize_stats(const float* __restrict__ ps,
                               const float* __restrict__ pq,
                               float* __restrict__ A, float* __restrict__ Bo,
                               float scale) {
  const int i = blockIdx.x * 256 + threadIdx.x;  // 4096
  const int b = i >> 8, c = i & 255;
  const float* s0 = ps + ((size_t)(b << 6) << 8) + c;
  const float* q0 = pq + ((size_t)(b << 6) << 8) + c;
  float s = 0.f, sq = 0.f;
#pragma unroll 8
  for (int j = 0; j < 64; ++j) {
    s += s0[(size_t)j << 8];
    sq += q0[(size_t)j << 8];
  }
  float m = s * (1.f / 4096.f);
  float v = sq * (1.f / 4096.f) - m * m;
  float a = rsqrtf(v + 1e-5f) * scale;
  A[i] = a;
  Bo[i] = -m * a;
}

// ---------------------------------------------------------------------------
// rpb + mask fused, MFMA D-fragment order.
// ---------------------------------------------------------------------------
__global__ __launch_bounds__(256) void rpbm_prep(const float* __restrict__ rpb,
                                                 float* __restrict__ rpbm) {
  const int idx = blockIdx.x * 256 + threadIdx.x;  // 131072
  const int t = idx & 63;
  const int lane = (idx >> 6) & 63;
  const int h = (idx >> 12) & 7;
  const int var = idx >> 15;
  const int cf = t >> 4, rf = (t >> 2) & 3, r = t & 3;
  const int n = ((lane >> 4) << 2) + r + (rf << 4);
  const int m = (lane & 15) + (cf << 4);
  const int vh = var >> 1, vw = var & 1;
  const int ln = (vh ? (1 + ((n >> 3) >= 4)) : 0) * 3 + (vw ? (1 + ((n & 7) >= 4)) : 0);
  const int lm = (vh ? (1 + ((m >> 3) >= 4)) : 0) * 3 + (vw ? (1 + ((m & 7) >= 4)) : 0);
  rpbm[idx] = rpb[(h << 12) + (n << 6) + m] + ((ln == lm) ? 0.f : -100.f);
}

// ---------------------------------------------------------------------------
// Proj weights -> bf16, fragment order pwf[cf][ks][g][u][8j]:
// oc = cf*16+u, ic = ks*32+g*8+j.
// ---------------------------------------------------------------------------
__global__ __launch_bounds__(256) void pwf_prep(const float* __restrict__ pW,
                                                u16* __restrict__ pwf) {
  const int idx = blockIdx.x * 256 + threadIdx.x;  // 8192
  const int u_ = idx & 15, g_ = (idx >> 4) & 3, ks_ = (idx >> 6) & 7,
            cf_ = idx >> 9;
  const int oc = (cf_ << 4) + u_, ic = (ks_ << 5) + (g_ << 3);
  const float* p = pW + (size_t)oc * 256 + ic;
  float4 v0 = *(const float4*)p;
  float4 v1 = *(const float4*)(p + 4);
  uint4 w;
  w.x = pk2(v0.x, v0.y); w.y = pk2(v0.z, v0.w);
  w.z = pk2(v1.x, v1.y); w.w = pk2(v1.z, v1.w);
  *(uint4*)(pwf + (size_t)idx * 8) = w;
}

// ---------------------------------------------------------------------------
// MFMA linear: dst = gather_window_shift(src) @ W^T + bias, stored bf16 in
// attention-fragment order. BM=128, BN=256, BK=64; 512 thr = 8 waves (2x4).
// MODE 0 (klin, grid.y=1): [win][h][cf][g][u][8j]   [+STATS partials]
// MODE 1 (vt, grid.y=2 selects branch): [win][h][df][ks][g][u][8j]
// ---------------------------------------------------------------------------
template <int MODE, int STATS>
__global__ __launch_bounds__(512) void gemm_lin(const float* src,
                                                const float* W,
                                                const float* bias,
                                                u16* dst,
                                                const float* src2,
                                                const float* W2,
                                                const float* bias2,
                                                u16* dst2,
                                                float* __restrict__ kps,
                                                float* __restrict__ kpq) {
  if (MODE == 1 && blockIdx.y == 1) {
    src = src2; W = W2; bias = bias2; dst = dst2;
  }
  __shared__ u16 A_s[128][72];
  __shared__ u16 B_s[256][72];
  const int t = threadIdx.x;
  const int r0 = blockIdx.x << 7;

  // A staging: 4 thr/row, 16 f32 each
  const int srowA = t >> 2;
  const int kA0 = (t & 3) << 4;
  const int rg = r0 + srowA;
  const int bb = rg >> 12;
  const int rr = rg & 4095;
  const int wi = rr >> 6;
  const int nn = rr & 63;
  const int hs = ((wi >> 3) << 3) + (nn >> 3);
  const int wsq = ((wi & 7) << 3) + (nn & 7);
  const size_t abase =
      (((size_t)((bb << 6) | ((hs + 4) & 63)) << 6) | ((wsq + 4) & 63)) << 8;
  // B staging: 2 thr/row, 32 f32 each
  const int srowB = t >> 1;
  const int kB0 = (t & 1) << 5;
  const size_t wbase = (size_t)srowB << 8;

  const int wid = t >> 6, l = t & 63, u = l & 15, g = l >> 4;
  const int wr = wid >> 2, wc = wid & 3;
  const int win = (blockIdx.x << 1) | wr;

  f32x4 acc[4][4];
#pragma unroll
  for (int i = 0; i < 4; ++i)
#pragma unroll
    for (int j = 0; j < 4; ++j) acc[i][j] = {0.f, 0.f, 0.f, 0.f};

  for (int kk = 0; kk < 256; kk += 64) {
    __syncthreads();
    {
      const float* ap = src + abase + kk + kA0;
#pragma unroll
      for (int j = 0; j < 2; ++j) {
        float4 v0 = *(const float4*)(ap + (j << 3));
        float4 v1 = *(const float4*)(ap + (j << 3) + 4);
        uint4 w;
        w.x = pk2(v0.x, v0.y); w.y = pk2(v0.z, v0.w);
        w.z = pk2(v1.x, v1.y); w.w = pk2(v1.z, v1.w);
        *(uint4*)&A_s[srowA][kA0 + (j << 3)] = w;
      }
      const float* bp = W + wbase + kk + kB0;
#pragma unroll
      for (int j = 0; j < 4; ++j) {
        float4 v0 = *(const float4*)(bp + (j << 3));
        float4 v1 = *(const float4*)(bp + (j << 3) + 4);
        uint4 x;
        x.x = pk2(v0.x, v0.y); x.y = pk2(v0.z, v0.w);
        x.z = pk2(v1.x, v1.y); x.w = pk2(v1.z, v1.w);
        *(uint4*)&B_s[srowB][kB0 + (j << 3)] = x;
      }
    }
    __syncthreads();
#pragma unroll
    for (int ks = 0; ks < 2; ++ks) {
      bf16x8 a[4], bq[4];
#pragma unroll
      for (int rf = 0; rf < 4; ++rf)
        a[rf] = *(const bf16x8*)&A_s[(wr << 6) + (rf << 4) + u][(ks << 5) + (g << 3)];
#pragma unroll
      for (int cf = 0; cf < 4; ++cf)
        bq[cf] = *(const bf16x8*)&B_s[(wc << 6) + (cf << 4) + u][(ks << 5) + (g << 3)];
#pragma unroll
      for (int rf = 0; rf < 4; ++rf)
#pragma unroll
        for (int cf = 0; cf < 4; ++cf)
          acc[rf][cf] = __builtin_amdgcn_mfma_f32_16x16x32_bf16(a[rf], bq[cf],
                                                                acc[rf][cf], 0, 0, 0);
    }
  }

#pragma unroll
  for (int cf = 0; cf < 4; ++cf) {
    const int col = (wc << 6) + (cf << 4) + u;
    const float bv = bias[col];
    float s = 0.f, sq = 0.f;
#pragma unroll
    for (int rf = 0; rf < 4; ++rf) {
      if (MODE == 0) {
        // klin: token t = (rf<<4) + (g<<2) + r ; channel = col
        const int hh = col >> 5;
        const int ga = (col >> 3) & 3;
        const int j = col & 7;
        const size_t base =
            ((size_t)((win << 3) | hh) << 11) + (rf << 9) + (ga << 7) + j;
#pragma unroll
        for (int r = 0; r < 4; ++r) {
          u16 hv = f2b(acc[rf][cf][r] + bv);
          dst[base + (((g << 2) + r) << 3)] = hv;
          if (STATS) {
            float rv = b2f(hv);
            s += rv;
            sq = fmaf(rv, rv, sq);
          }
        }
      } else {
        // vt: d-channel = col, token t = (rf<<4)+(g<<2)+r
        const int hh = (wc << 1) | (cf >> 1);
        const int df = cf & 1;
        const int ks = rf >> 1;
        const int ga = ((rf & 1) << 1) | (g >> 1);
        const size_t base = ((size_t)((win << 3) | hh) << 11) + (df << 10) +
                            (ks << 9) + (ga << 7) + (u << 3) + ((g & 1) << 2);
        u32 w0 = pk2(acc[rf][cf][0] + bv, acc[rf][cf][1] + bv);
        u32 w1 = pk2(acc[rf][cf][2] + bv, acc[rf][cf][3] + bv);
        *(uint2*)(dst + base) = make_uint2(w0, w1);
      }
    }
    if (MODE == 0 && STATS) {
      s += __shfl_xor(s, 16);
      s += __shfl_xor(s, 32);
      sq += __shfl_xor(sq, 16);
      sq += __shfl_xor(sq, 32);
      if (g == 0) {
        const int row = (blockIdx.x << 1) | wr;   // 0..1023, b = row>>6
        kps[(row << 8) + col] = s;
        kpq[(row << 8) + col] = sq;
      }
    }
  }
}

// ---------------------------------------------------------------------------
// Fused attention + projection. Block = window (1024), 512 thr = 8 waves,
// wave = head. QK^T -> softmax -> P (per-wave LDS) -> per branch:
// PV -> X bf16 in shared LDS -> barrier -> cooperative proj (wave owns 32
// output channels) -> reverse-shift f32 scatter -> barrier.
// ---------------------------------------------------------------------------
__global__ __launch_bounds__(512) void attn_mega(
    const float* __restrict__ qsrc, const float* __restrict__ qA_,
    const float* __restrict__ qB_, const u16* __restrict__ klin,
    const float* __restrict__ kA_, const float* __restrict__ kB_,
    const u16* __restrict__ vt, const float* __restrict__ rpbm,
    const u16* __restrict__ pwf, const float* __restrict__ pbias,
    float* __restrict__ outp) {
  __shared__ u16 P[8][64][72];   // 73.7 KB
  __shared__ u16 Xl[64][264];    // 33.8 KB
  const int tid = threadIdx.x;
  const int wid = tid >> 6;      // head
  const int l = tid & 63;
  const int u = l & 15;
  const int g = l >> 4;
  const int win = blockIdx.x;
  const int h = wid;
  const int b = win >> 6;
  const int wIdx = win & 63;
  const int wh = wIdx >> 3, ww = wIdx & 7;
  const int var = ((wh == 7) ? 2 : 0) | ((ww == 7) ? 1 : 0);
  const int coff = (h << 5) + (g << 3);

  float qav[8], qbv[8], kav[8], kbv[8];
  {
    const int o = (b << 8) + coff;
    float4 a0 = *(const float4*)(qA_ + o), a1 = *(const float4*)(qA_ + o + 4);
    float4 b0 = *(const float4*)(qB_ + o), b1 = *(const float4*)(qB_ + o + 4);
    float4 c0v = *(const float4*)(kA_ + o), c1 = *(const float4*)(kA_ + o + 4);
    float4 d0v = *(const float4*)(kB_ + o), d1 = *(const float4*)(kB_ + o + 4);
    qav[0]=a0.x;qav[1]=a0.y;qav[2]=a0.z;qav[3]=a0.w;qav[4]=a1.x;qav[5]=a1.y;qav[6]=a1.z;qav[7]=a1.w;
    qbv[0]=b0.x;qbv[1]=b0.y;qbv[2]=b0.z;qbv[3]=b0.w;qbv[4]=b1.x;qbv[5]=b1.y;qbv[6]=b1.z;qbv[7]=b1.w;
    kav[0]=c0v.x;kav[1]=c0v.y;kav[2]=c0v.z;kav[3]=c0v.w;kav[4]=c1.x;kav[5]=c1.y;kav[6]=c1.z;kav[7]=c1.w;
    kbv[0]=d0v.x;kbv[1]=d0v.y;kbv[2]=d0v.z;kbv[3]=d0v.w;kbv[4]=d1.x;kbv[5]=d1.y;kbv[6]=d1.z;kbv[7]=d1.w;
  }

  // q fragments (gathered + normalized + scaled)
  bf16x8 qf[4];
#pragma unroll
  for (int rf = 0; rf < 4; ++rf) {
    const int n = (rf << 4) + u;
    const int nhs = (wh << 3) + (n >> 3);
    const int nws = (ww << 3) + (n & 7);
    const float* qp = qsrc +
        ((((size_t)((b << 6) | ((nhs + 4) & 63)) << 6) | ((nws + 4) & 63)) << 8) + coff;
    float4 v0 = *(const float4*)qp;
    float4 v1 = *(const float4*)(qp + 4);
    float qv[8] = {v0.x, v0.y, v0.z, v0.w, v1.x, v1.y, v1.z, v1.w};
#pragma unroll
    for (int j = 0; j < 8; ++j) qf[rf][j] = (short)f2b(fmaf(qv[j], qav[j], qbv[j]));
  }

  // k fragments — fragment-ordered klin: wave read = 64 lanes x 16B contiguous
  const u16* kp = klin + ((size_t)((win << 3) | h) << 11);
  bf16x8 kf[4];
#pragma unroll
  for (int cf = 0; cf < 4; ++cf) {
    union { uint4 v; u16 s[8]; } raw;
    raw.v = *(const uint4*)(kp + (cf << 9) + (g << 7) + (u << 3));
#pragma unroll
    for (int j = 0; j < 8; ++j)
      kf[cf][j] = (short)f2b(fmaf(b2f(raw.s[j]), kav[j], kbv[j]));
  }

  // S = q k^T
  f32x4 s[4][4];
  const f32x4 z4 = {0.f, 0.f, 0.f, 0.f};
#pragma unroll
  for (int rf = 0; rf < 4; ++rf)
#pragma unroll
    for (int cf = 0; cf < 4; ++cf)
      s[rf][cf] = __builtin_amdgcn_mfma_f32_16x16x32_bf16(qf[rf], kf[cf], z4, 0, 0, 0);

  // + rpb + mask (pre-fused, fragment order)
  const float* rb = rpbm + ((((var << 3) + h) << 6) + l) * 64;
#pragma unroll
  for (int cf = 0; cf < 4; ++cf)
#pragma unroll
    for (int rf = 0; rf < 4; ++rf) {
      float4 bv = *(const float4*)(rb + (cf << 4) + (rf << 2));
      s[rf][cf][0] += bv.x; s[rf][cf][1] += bv.y;
      s[rf][cf][2] += bv.z; s[rf][cf][3] += bv.w;
    }

  // softmax over m (4 col-frags x 16 lanes)
  f32x4 inv[4];
#pragma unroll
  for (int rf = 0; rf < 4; ++rf) {
#pragma unroll
    for (int r = 0; r < 4; ++r) {
      float m0 = fmaxf(fmaxf(s[rf][0][r], s[rf][1][r]),
                       fmaxf(s[rf][2][r], s[rf][3][r]));
      m0 = fmaxf(m0, __shfl_xor(m0, 1));
      m0 = fmaxf(m0, __shfl_xor(m0, 2));
      m0 = fmaxf(m0, __shfl_xor(m0, 4));
      m0 = fmaxf(m0, __shfl_xor(m0, 8));
      float t0 = 0.f;
#pragma unroll
      for (int cf = 0; cf < 4; ++cf) {
        s[rf][cf][r] = __expf(s[rf][cf][r] - m0);
        t0 += s[rf][cf][r];
      }
      t0 += __shfl_xor(t0, 1);
      t0 += __shfl_xor(t0, 2);
      t0 += __shfl_xor(t0, 4);
      t0 += __shfl_xor(t0, 8);
      inv[rf][r] = 1.f / t0;
    }
  }

  // P -> LDS (row-major [n][m], bf16, per-wave private)
#pragma unroll
  for (int rf = 0; rf < 4; ++rf)
#pragma unroll
    for (int r = 0; r < 4; ++r) {
      const int n = (rf << 4) + (g << 2) + r;
#pragma unroll
      for (int cf = 0; cf < 4; ++cf)
        P[wid][n][(cf << 4) + u] = f2b(s[rf][cf][r] * inv[rf][r]);
    }

  // per-branch: PV -> X LDS -> barrier -> proj -> store -> barrier
#pragma unroll 1
  for (int br = 0; br < 2; ++br) {
    const u16* vb = vt + (size_t)br * 16777216 + ((size_t)((win << 3) | h) << 11);
    bf16x8 vf[2][2];
#pragma unroll
    for (int df = 0; df < 2; ++df)
#pragma unroll
      for (int ks = 0; ks < 2; ++ks)
        vf[df][ks] = *(const bf16x8*)(vb + (df << 10) + (ks << 9) + (g << 7) + (u << 3));
    f32x4 xt[2][4];
#pragma unroll
    for (int df = 0; df < 2; ++df)
#pragma unroll
      for (int cf = 0; cf < 4; ++cf) xt[df][cf] = z4;
#pragma unroll
    for (int cf = 0; cf < 4; ++cf)
#pragma unroll
      for (int ks = 0; ks < 2; ++ks) {
        bf16x8 pf = *(const bf16x8*)&P[wid][(cf << 4) + u][(ks << 5) + (g << 3)];
        xt[0][cf] = __builtin_amdgcn_mfma_f32_16x16x32_bf16(vf[0][ks], pf, xt[0][cf], 0, 0, 0);
        xt[1][cf] = __builtin_amdgcn_mfma_f32_16x16x32_bf16(vf[1][ks], pf, xt[1][cf], 0, 0, 0);
      }
    // X -> LDS: tok = cf*16+u, ch = h*32 + df*16 + g*4 + r
#pragma unroll
    for (int df = 0; df < 2; ++df)
#pragma unroll
      for (int cf = 0; cf < 4; ++cf) {
        const int tok = (cf << 4) + u;
        const int ch = (h << 5) + (df << 4) + (g << 2);
        *(u32*)&Xl[tok][ch] = pk2(xt[df][cf][0], xt[df][cf][1]);
        *(u32*)&Xl[tok][ch + 2] = pk2(xt[df][cf][2], xt[df][cf][3]);
      }
    __syncthreads();

    // cooperative proj: wave wid owns oc in [32*wid, 32*wid+32)
    f32x4 acc[4][2];
#pragma unroll
    for (int mf = 0; mf < 4; ++mf)
#pragma unroll
      for (int cfi = 0; cfi < 2; ++cfi) acc[mf][cfi] = z4;
#pragma unroll
    for (int ks = 0; ks < 8; ++ks) {
      bf16x8 a[4];
#pragma unroll
      for (int mf = 0; mf < 4; ++mf)
        a[mf] = *(const bf16x8*)&Xl[(mf << 4) + u][(ks << 5) + (g << 3)];
      bf16x8 bw[2];
#pragma unroll
      for (int cfi = 0; cfi < 2; ++cfi) {
        const int cf = (wid << 1) | cfi;
        bw[cfi] = *(const bf16x8*)(pwf +
            ((((((size_t)(cf << 3) | ks) << 2) | g) << 4 | u) << 3));
      }
#pragma unroll
      for (int mf = 0; mf < 4; ++mf)
#pragma unroll
        for (int cfi = 0; cfi < 2; ++cfi)
          acc[mf][cfi] = __builtin_amdgcn_mfma_f32_16x16x32_bf16(a[mf], bw[cfi],
                                                                 acc[mf][cfi], 0, 0, 0);
    }

    // epilogue: +bias, reverse-shift scatter
    float* ob = outp + (size_t)br * 16777216;
#pragma unroll
    for (int cfi = 0; cfi < 2; ++cfi) {
      const int oc = (((wid << 1) | cfi) << 4) + u;
      const float bv = pbias[oc];
#pragma unroll
      for (int mf = 0; mf < 4; ++mf) {
#pragma unroll
        for (int r = 0; r < 4; ++r) {
          const int tok = (mf << 4) + (g << 2) + r;
          const int nhs = (wh << 3) + (tok >> 3);
          const int nws = (ww << 3) + (tok & 7);
          ob[((((size_t)((b << 6) | ((nhs + 4) & 63)) << 6) |
               ((nws + 4) & 63)) << 8) + oc] = acc[mf][cfi][r] + bv;
        }
      }
    }
    __syncthreads();  // Xl reuse by next branch
  }
}

// ---------------------------------------------------------------------------
extern "C" void kernel_launch(void* const* d_in, const int* in_sizes, int n_in,
                              void* d_out, int out_size, void* d_ws,
                              size_t ws_size, hipStream_t stream) {
  (void)in_sizes; (void)n_in; (void)out_size; (void)ws_size;
  const float* q   = (const float*)d_in[0];
  const float* k   = (const float*)d_in[1];
  const float* vs  = (const float*)d_in[2];
  const float* vsh = (const float*)d_in[3];
  const float* kW  = (const float*)d_in[4];
  const float* kb  = (const float*)d_in[5];
  const float* vWs = (const float*)d_in[6];
  const float* vbs = (const float*)d_in[7];
  const float* vWh = (const float*)d_in[8];
  const float* vbh = (const float*)d_in[9];
  const float* pW  = (const float*)d_in[10];
  const float* pb  = (const float*)d_in[11];
  const float* rpb = (const float*)d_in[12];
  float* out = (float*)d_out;

  float* f = (float*)d_ws;
  float* qps = f;                       // 262144
  float* qpq = f + 262144;              // 262144
  float* kps = f + 524288;              // 262144
  float* kpq = f + 786432;              // 262144
  float* qA  = f + 1048576;
  float* qB  = f + 1052672;
  float* kA  = f + 1056768;
  float* kB  = f + 1060864;
  float* rpbm = f + 1064960;            // 131072
  u16* klin = (u16*)(f + 1196032);      // 16.77M u16
  u16* vt   = (u16*)(f + 9584640);      // 33.55M u16 (2 branches)
  u16* pwf  = (u16*)(f + 26361856);     // 65536 u16

  stats_f32<<<1024, 256, 0, stream>>>(q, qps, qpq);
  finalize_stats<<<16, 256, 0, stream>>>(qps, qpq, qA, qB,
                                         0.17677669529663687f);  // 1/sqrt(32)
  rpbm_prep<<<512, 256, 0, stream>>>(rpb, rpbm);
  pwf_prep<<<32, 256, 0, stream>>>(pW, pwf);

  gemm_lin<0, 1><<<512, 512, 0, stream>>>(k, kW, kb, klin,
                                          nullptr, nullptr, nullptr, nullptr,
                                          kps, kpq);
  finalize_stats<<<16, 256, 0, stream>>>(kps, kpq, kA, kB, 1.0f);

  gemm_lin<1, 0><<<dim3(512, 2), 512, 0, stream>>>(vs, vWs, vbs, vt,
                                                   vsh, vWh, vbh, vt + 16777216,
                                                   nullptr, nullptr);

  attn_mega<<<1024, 512, 0, stream>>>(q, qA, qB, klin, kA, kB, vt, rpbm,
                                      pwf, pb, out);
}